// Round 13
// baseline (79.983 us; speedup 1.0000x reference)
//
#include <hip/hip_runtime.h>
#include <math.h>

#define NPOINTS 32768
#define NPRIMS  2048
#define BLK     256
#define NCELLS  4096          // 16^3 Morton cells

typedef float v2f __attribute__((ext_vector_type(2)));

// 64-byte record for ONE primitive, scalars duplicated for SGPR-pair
// broadcast into VOP3P (R10-verified layout).
//  q0 = (mux, mux, muy, muy)
//  q1 = (muz, muz, amp, amp)
//  q2 = (gx,  gx,  gy,  gy )   g = -0.5*log2(e)/s^2  (NEGATIVE)
//  q3 = (gz,  gz,  ph,  ph )   ph in revolutions
struct PrimDup { float4 q0, q1, q2, q3; };

__device__ __forceinline__ float read_freq(const void* p) {
    const unsigned* w = (const unsigned*)p;
    unsigned lo = w[0];
    float ff = __uint_as_float(lo);
    if (ff >= 1.0e5f && ff <= 1.0e13f) return ff;
    if (lo != 0u) return (float)lo;
    double d = *(const double*)p;
    if (d >= 1.0e5 && d <= 1.0e13) return (float)d;
    unsigned long long v = ((unsigned long long)w[1] << 32) | lo;
    return (float)v;
}

__global__ __launch_bounds__(BLK) void prep_kernel(
        const float* __restrict__ pos, const float* __restrict__ scl,
        const float* __restrict__ amp, const float* __restrict__ ph,
        PrimDup* __restrict__ pd) {
    int p = blockIdx.x * blockDim.x + threadIdx.x;
    if (p >= NPRIMS) return;
    const float KE = -0.72134752044448169f, INV2PI = 0.15915494309189535f;
    float sx = scl[3*p+0], sy = scl[3*p+1], sz = scl[3*p+2];
    PrimDup D;
    D.q0 = make_float4(pos[3*p+0], pos[3*p+0], pos[3*p+1], pos[3*p+1]);
    D.q1 = make_float4(pos[3*p+2], pos[3*p+2], amp[p], amp[p]);
    D.q2 = make_float4(KE/(sx*sx), KE/(sx*sx), KE/(sy*sy), KE/(sy*sy));
    D.q3 = make_float4(KE/(sz*sz), KE/(sz*sz), ph[p]*INV2PI, ph[p]*INV2PI);
    pd[p] = D;
}

// ---------- Morton counting sort of query points ----------
__device__ __forceinline__ unsigned sp4(unsigned b) {   // spread 4 bits
    return (b & 1u) | ((b & 2u) << 2) | ((b & 4u) << 4) | ((b & 8u) << 6);
}
__device__ __forceinline__ unsigned cell_of(float x, float y, float z) {
    int qx = (int)((x + 6.4f) * 1.25f); qx = qx < 0 ? 0 : (qx > 15 ? 15 : qx);
    int qy = (int)((y + 6.4f) * 1.25f); qy = qy < 0 ? 0 : (qy > 15 ? 15 : qy);
    int qz = (int)((z + 6.4f) * 1.25f); qz = qz < 0 ? 0 : (qz > 15 ? 15 : qz);
    return sp4((unsigned)qx) | (sp4((unsigned)qy) << 1) | (sp4((unsigned)qz) << 2);
}

__global__ __launch_bounds__(BLK) void zero_hist(unsigned* __restrict__ hist) {
    int i = blockIdx.x * blockDim.x + threadIdx.x;
    if (i < NCELLS) hist[i] = 0;
}

__global__ __launch_bounds__(BLK) void hist_kernel(
        const float* __restrict__ qp, unsigned* __restrict__ hist,
        unsigned* __restrict__ cellid) {
    int n = blockIdx.x * blockDim.x + threadIdx.x;
    unsigned c = cell_of(qp[3*n+0], qp[3*n+1], qp[3*n+2]);
    cellid[n] = c;
    atomicAdd(&hist[c], 1u);
}

__global__ __launch_bounds__(BLK) void scan_kernel(unsigned* __restrict__ hist) {
    __shared__ unsigned tot[BLK];
    const int t = threadIdx.x;                 // 1 block of 256; 16 bins each
    unsigned loc[16]; unsigned s = 0;
    #pragma unroll
    for (int i = 0; i < 16; ++i) { loc[i] = hist[t*16 + i]; s += loc[i]; }
    tot[t] = s;
    __syncthreads();
    for (int off = 1; off < BLK; off <<= 1) {
        unsigned u = (t >= off) ? tot[t - off] : 0u;
        __syncthreads();
        tot[t] += u;
        __syncthreads();
    }
    unsigned run = tot[t] - s;                 // exclusive base
    #pragma unroll
    for (int i = 0; i < 16; ++i) { hist[t*16 + i] = run; run += loc[i]; }
}

__global__ __launch_bounds__(BLK) void scatter_kernel(
        const float* __restrict__ qp, const unsigned* __restrict__ cellid,
        unsigned* __restrict__ off, float4* __restrict__ sxyz,
        unsigned* __restrict__ sidx) {
    int n = blockIdx.x * blockDim.x + threadIdx.x;
    unsigned pos = atomicAdd(&off[cellid[n]], 1u);
    sxyz[pos] = make_float4(qp[3*n+0], qp[3*n+1], qp[3*n+2], 0.0f);
    sidx[pos] = (unsigned)n;
}

// ---------- field over sorted points with per-wave AABB cull ----------
// Each wave: 128 consecutive sorted points (2/thread, v2f). Per prim:
// conservative bound e <= sum g_d * t_d^2 (g<0); skip body if < -21
// (skipped contribution < 2048 * 2^-21 ~ 1e-3 << 0.0156 tolerance).
template <int NSPLIT>
__global__ __launch_bounds__(BLK) void field_sorted(
        const float4* __restrict__ sxyz,
        const PrimDup* __restrict__ pd,
        const void* __restrict__ freq_p,
        float2* __restrict__ part) {
    constexpr int PCOUNT = NPRIMS / NSPLIT;
    const int lane = threadIdx.x & 63;
    const int wid  = threadIdx.x >> 6;
    const int base = blockIdx.x * (BLK * 2) + wid * 128;
    const int i0 = base + lane, i1 = base + 64 + lane;

    const float4 p0 = sxyz[i0], p1 = sxyz[i1];
    const float kr = read_freq(freq_p) / 299792458.0f;
    const v2f kr2 = {kr, kr};
    const v2f xx = {p0.x, p1.x}, yy = {p0.y, p1.y}, zz = {p0.z, p1.z};

    // wave AABB via shuffle-xor reduce (once per wave)
    float mnx = fminf(p0.x, p1.x), mxx = fmaxf(p0.x, p1.x);
    float mny = fminf(p0.y, p1.y), mxy = fmaxf(p0.y, p1.y);
    float mnz = fminf(p0.z, p1.z), mxz = fmaxf(p0.z, p1.z);
    #pragma unroll
    for (int m = 1; m < 64; m <<= 1) {
        mnx = fminf(mnx, __shfl_xor(mnx, m, 64));
        mxx = fmaxf(mxx, __shfl_xor(mxx, m, 64));
        mny = fminf(mny, __shfl_xor(mny, m, 64));
        mxy = fmaxf(mxy, __shfl_xor(mxy, m, 64));
        mnz = fminf(mnz, __shfl_xor(mnz, m, 64));
        mxz = fmaxf(mxz, __shfl_xor(mxz, m, 64));
    }
    const float cx = 0.5f*(mnx+mxx), ex = 0.5f*(mxx-mnx);
    const float cy = 0.5f*(mny+mxy), ey = 0.5f*(mxy-mny);
    const float cz = 0.5f*(mnz+mxz), ez = 0.5f*(mxz-mnz);

    v2f re = {0.0f, 0.0f}, im = {0.0f, 0.0f};
    const int pb = blockIdx.y * PCOUNT;
    #pragma unroll 2
    for (int j = 0; j < PCOUNT; ++j) {
        PrimDup D = pd[pb + j];                // wave-uniform -> s_load x16
        // conservative wave-level bound (uniform across lanes)
        float tx = fmaxf(fabsf(cx - D.q0.x) - ex, 0.0f);
        float ty = fmaxf(fabsf(cy - D.q0.z) - ey, 0.0f);
        float tz = fmaxf(fabsf(cz - D.q1.x) - ez, 0.0f);
        float bound = tx*tx*D.q2.x + ty*ty*D.q2.z + tz*tz*D.q3.x;  // <= e, negative
        if (bound > -21.0f) {
            v2f mux = {D.q0.x, D.q0.y}, muy = {D.q0.z, D.q0.w};
            v2f muz = {D.q1.x, D.q1.y}, am2 = {D.q1.z, D.q1.w};
            v2f gx  = {D.q2.x, D.q2.y}, gy  = {D.q2.z, D.q2.w};
            v2f gz  = {D.q3.x, D.q3.y}, ph2 = {D.q3.z, D.q3.w};

            v2f dx = xx - mux, dy = yy - muy, dz = zz - muz;
            v2f t0 = dx * dx, t1 = dy * dy, t2 = dz * dz;
            v2f e  = t0 * gx + t1 * gy + t2 * gz;
            v2f d2 = t0 + t1 + t2;
            d2 = __builtin_elementwise_max(d2, (v2f){1e-12f, 1e-12f});

            v2f r2 = {__builtin_amdgcn_sqrtf(d2.x), __builtin_amdgcn_sqrtf(d2.y)};
            v2f exw = {__builtin_amdgcn_exp2f(e.x), __builtin_amdgcn_exp2f(e.y)};
            v2f w2 = am2 * exw;
            v2f tp = __builtin_elementwise_fma(kr2, r2, ph2);
            float f0 = __builtin_amdgcn_fractf(tp.x);
            float f1 = __builtin_amdgcn_fractf(tp.y);
            v2f s2 = {__builtin_amdgcn_sinf(f0), __builtin_amdgcn_sinf(f1)};
            v2f c2 = {__builtin_amdgcn_cosf(f0), __builtin_amdgcn_cosf(f1)};
            re = __builtin_elementwise_fma(w2, c2, re);
            im = __builtin_elementwise_fma(w2, s2, im);
        }
    }

    part[(size_t)blockIdx.y * NPOINTS + i0] = make_float2(re.x, im.x);
    part[(size_t)blockIdx.y * NPOINTS + i1] = make_float2(re.y, im.y);
}

template <int NSPLIT>
__global__ __launch_bounds__(BLK) void reduce_sorted(
        const float2* __restrict__ part, const unsigned* __restrict__ sidx,
        float* __restrict__ out) {
    int pos = blockIdx.x * blockDim.x + threadIdx.x;
    float re = 0.0f, im = 0.0f;
    #pragma unroll
    for (int s = 0; s < NSPLIT; ++s) {
        float2 v = part[(size_t)s * NPOINTS + pos];
        re += v.x; im += v.y;
    }
    unsigned n = sidx[pos];
    out[n]           = re;
    out[NPOINTS + n] = im;
}

// ---------- R10 path (known 44.1 us field) for smaller workspace ----------
template <int NSPLIT>
__global__ __launch_bounds__(BLK) void field_kernel(
        const float* __restrict__ qp, const PrimDup* __restrict__ pd,
        const void* __restrict__ freq_p, float2* __restrict__ part) {
    constexpr int PCOUNT = NPRIMS / NSPLIT;
    const int n0 = blockIdx.x * (BLK * 2) + threadIdx.x;
    const int n1 = n0 + BLK;
    const float kr = read_freq(freq_p) / 299792458.0f;
    const v2f kr2 = {kr, kr};
    const v2f xx = {qp[3*n0+0], qp[3*n1+0]};
    const v2f yy = {qp[3*n0+1], qp[3*n1+1]};
    const v2f zz = {qp[3*n0+2], qp[3*n1+2]};
    v2f re = {0.0f, 0.0f}, im = {0.0f, 0.0f};
    const int base = blockIdx.y * PCOUNT;
    #pragma unroll 4
    for (int j = 0; j < PCOUNT; ++j) {
        PrimDup D = pd[base + j];
        v2f mux = {D.q0.x, D.q0.y}, muy = {D.q0.z, D.q0.w};
        v2f muz = {D.q1.x, D.q1.y}, am2 = {D.q1.z, D.q1.w};
        v2f gx  = {D.q2.x, D.q2.y}, gy  = {D.q2.z, D.q2.w};
        v2f gz  = {D.q3.x, D.q3.y}, ph2 = {D.q3.z, D.q3.w};
        v2f dx = xx - mux, dy = yy - muy, dz = zz - muz;
        v2f t0 = dx * dx, t1 = dy * dy, t2 = dz * dz;
        v2f e  = t0 * gx + t1 * gy + t2 * gz;
        v2f d2 = t0 + t1 + t2;
        d2 = __builtin_elementwise_max(d2, (v2f){1e-12f, 1e-12f});
        v2f r2 = {__builtin_amdgcn_sqrtf(d2.x), __builtin_amdgcn_sqrtf(d2.y)};
        v2f ex = {__builtin_amdgcn_exp2f(e.x),  __builtin_amdgcn_exp2f(e.y)};
        v2f w2 = am2 * ex;
        v2f tp = __builtin_elementwise_fma(kr2, r2, ph2);
        float f0 = __builtin_amdgcn_fractf(tp.x);
        float f1 = __builtin_amdgcn_fractf(tp.y);
        v2f s2 = {__builtin_amdgcn_sinf(f0), __builtin_amdgcn_sinf(f1)};
        v2f c2 = {__builtin_amdgcn_cosf(f0), __builtin_amdgcn_cosf(f1)};
        re = __builtin_elementwise_fma(w2, c2, re);
        im = __builtin_elementwise_fma(w2, s2, im);
    }
    part[(size_t)blockIdx.y * NPOINTS + n0] = make_float2(re.x, im.x);
    part[(size_t)blockIdx.y * NPOINTS + n1] = make_float2(re.y, im.y);
}

template <int NSPLIT>
__global__ __launch_bounds__(BLK) void reduce_kernel(const float2* __restrict__ part,
                                                     float* __restrict__ out) {
    int n = blockIdx.x * blockDim.x + threadIdx.x;
    float re = 0.0f, im = 0.0f;
    #pragma unroll
    for (int s = 0; s < NSPLIT; ++s) {
        float2 v = part[(size_t)s * NPOINTS + n];
        re += v.x; im += v.y;
    }
    out[n]           = re;
    out[NPOINTS + n] = im;
}

__global__ __launch_bounds__(BLK) void field_fallback(
        const float* __restrict__ qp, const float* __restrict__ pos,
        const float* __restrict__ scl, const float* __restrict__ amp,
        const float* __restrict__ ph, const void* __restrict__ freq_p,
        float* __restrict__ out) {
    __shared__ float4 sA[128];
    __shared__ float4 sB[128];
    const int n = blockIdx.x * BLK + threadIdx.x;
    const float x = qp[3*n+0], y = qp[3*n+1], z = qp[3*n+2];
    const float kr = read_freq(freq_p) / 299792458.0f;
    const float KE = -0.72134752044448169f, INV2PI = 0.15915494309189535f;
    float re = 0.0f, im = 0.0f;
    for (int tile = 0; tile < NPRIMS / 128; ++tile) {
        __syncthreads();
        if (threadIdx.x < 128) {
            int p = tile * 128 + threadIdx.x;
            float sx = scl[3*p+0], sy = scl[3*p+1], sz = scl[3*p+2];
            sA[threadIdx.x] = make_float4(pos[3*p+0], pos[3*p+1], pos[3*p+2], amp[p]);
            sB[threadIdx.x] = make_float4(KE/(sx*sx), KE/(sy*sy), KE/(sz*sz), ph[p]*INV2PI);
        }
        __syncthreads();
        #pragma unroll 8
        for (int p = 0; p < 128; ++p) {
            float4 a = sA[p]; float4 b = sB[p];
            float dx = x - a.x, dy = y - a.y, dz = z - a.z;
            float t0 = dx*dx, t1 = dy*dy, t2 = dz*dz;
            float e  = fmaf(t0, b.x, fmaf(t1, b.y, t2 * b.z));
            float d2 = t0 + t1 + t2;
            float r  = __builtin_amdgcn_sqrtf(fmaxf(d2, 1e-12f));
            float w  = a.w * __builtin_amdgcn_exp2f(e);
            float tp = __builtin_amdgcn_fractf(fmaf(kr, r, b.w));
            float s  = __builtin_amdgcn_sinf(tp);
            float c  = __builtin_amdgcn_cosf(tp);
            re = fmaf(w, c, re);
            im = fmaf(w, s, im);
        }
    }
    out[n]           = re;
    out[NPOINTS + n] = im;
}

extern "C" void kernel_launch(void* const* d_in, const int* in_sizes, int n_in,
                              void* d_out, int out_size, void* d_ws, size_t ws_size,
                              hipStream_t stream) {
    const float* qp  = (const float*)d_in[0];
    const float* pos = (const float*)d_in[1];
    const float* scl = (const float*)d_in[2];
    const float* amp = (const float*)d_in[3];
    const float* ph  = (const float*)d_in[4];
    const void*  fq  = d_in[5];
    float* out = (float*)d_out;

    // workspace layout (sorted path)
    const size_t pd_b   = (size_t)NPRIMS * sizeof(PrimDup);      // 128 KB
    const size_t hist_b = (size_t)NCELLS * 4;                    // 16 KB
    const size_t cid_b  = (size_t)NPOINTS * 4;                   // 128 KB
    const size_t sxyz_b = (size_t)NPOINTS * 16;                  // 512 KB
    const size_t sidx_b = (size_t)NPOINTS * 4;                   // 128 KB
    const size_t head   = pd_b + hist_b + cid_b + sxyz_b + sidx_b;
    const size_t sorted_need = head + (size_t)32 * NPOINTS * sizeof(float2); // +8 MB
    const size_t r10_need = pd_b + (size_t)32 * NPOINTS * sizeof(float2);

    if (ws_size >= sorted_need) {
        char* w = (char*)d_ws;
        PrimDup*  pd   = (PrimDup*)w;                 w += pd_b;
        unsigned* hist = (unsigned*)w;                w += hist_b;
        unsigned* cid  = (unsigned*)w;                w += cid_b;
        float4*   sxyz = (float4*)w;                  w += sxyz_b;
        unsigned* sidx = (unsigned*)w;                w += sidx_b;
        float2*   part = (float2*)w;

        prep_kernel<<<dim3(NPRIMS / BLK), dim3(BLK), 0, stream>>>(pos, scl, amp, ph, pd);
        zero_hist<<<dim3(NCELLS / BLK), dim3(BLK), 0, stream>>>(hist);
        hist_kernel<<<dim3(NPOINTS / BLK), dim3(BLK), 0, stream>>>(qp, hist, cid);
        scan_kernel<<<dim3(1), dim3(BLK), 0, stream>>>(hist);
        scatter_kernel<<<dim3(NPOINTS / BLK), dim3(BLK), 0, stream>>>(qp, cid, hist, sxyz, sidx);
        field_sorted<32><<<dim3(NPOINTS / (BLK * 2), 32), dim3(BLK), 0, stream>>>(sxyz, pd, fq, part);
        reduce_sorted<32><<<dim3(NPOINTS / BLK), dim3(BLK), 0, stream>>>(part, sidx, out);
    } else if (ws_size >= r10_need) {
        PrimDup* pd   = (PrimDup*)d_ws;
        float2*  part = (float2*)((char*)d_ws + pd_b);
        prep_kernel<<<dim3(NPRIMS / BLK), dim3(BLK), 0, stream>>>(pos, scl, amp, ph, pd);
        field_kernel<32><<<dim3(NPOINTS / (BLK * 2), 32), dim3(BLK), 0, stream>>>(qp, pd, fq, part);
        reduce_kernel<32><<<dim3(NPOINTS / BLK), dim3(BLK), 0, stream>>>(part, out);
    } else {
        field_fallback<<<dim3(NPOINTS / BLK), dim3(BLK), 0, stream>>>(qp, pos, scl, amp, ph, fq, out);
    }
}

// Round 14
// 45.564 us; speedup vs baseline: 1.7554x; 1.7554x over previous
//
#include <hip/hip_runtime.h>
#include <math.h>

#define NPOINTS 32768
#define NPRIMS  2048
#define BLK     256
#define PBLK    (NPOINTS / BLK)   // 128 point-blocks

typedef float v2f __attribute__((ext_vector_type(2)));

// 64-byte packed record for a pair of primitives (SoA-in-pairs) — the R6
// layout (best measured: field 42.8 us, total 47.3 us):
//  q0 = (mux0, mux1, muy0, muy1)
//  q1 = (muz0, muz1, amp0, amp1)
//  q2 = (gx0,  gx1,  gy0,  gy1 )   g = -0.5*log2(e)/s^2
//  q3 = (gz0,  gz1,  ph0,  ph1 )   ph in revolutions (phase/2pi)
struct PrimPair { float4 q0, q1, q2, q3; };

// Robust scalar-frequency decode (2400000000 in any plausible encoding).
__device__ __forceinline__ float read_freq(const void* p) {
    const unsigned* w = (const unsigned*)p;
    unsigned lo = w[0];
    float ff = __uint_as_float(lo);
    if (ff >= 1.0e5f && ff <= 1.0e13f) return ff;       // float32
    if (lo != 0u) return (float)lo;                      // int32-wrap / int64 lo
    double d = *(const double*)p;                        // lo==0 -> 8-byte dtype
    if (d >= 1.0e5 && d <= 1.0e13) return (float)d;      // float64
    unsigned long long v = ((unsigned long long)w[1] << 32) | lo;
    return (float)v;                                     // int64 (hi-word path)
}

__global__ __launch_bounds__(BLK) void prep_kernel(
        const float* __restrict__ pos,
        const float* __restrict__ scl,
        const float* __restrict__ amp,
        const float* __restrict__ ph,
        PrimPair* __restrict__ pp) {
    int j = blockIdx.x * blockDim.x + threadIdx.x;
    if (j >= NPRIMS / 2) return;
    const float KE     = -0.72134752044448169f;   // -0.5*log2(e)
    const float INV2PI =  0.15915494309189535f;
    int p0 = 2 * j, p1 = 2 * j + 1;
    float s0x = scl[3*p0+0], s0y = scl[3*p0+1], s0z = scl[3*p0+2];
    float s1x = scl[3*p1+0], s1y = scl[3*p1+1], s1z = scl[3*p1+2];
    PrimPair P;
    P.q0 = make_float4(pos[3*p0+0], pos[3*p1+0], pos[3*p0+1], pos[3*p1+1]);
    P.q1 = make_float4(pos[3*p0+2], pos[3*p1+2], amp[p0], amp[p1]);
    P.q2 = make_float4(KE / (s0x*s0x), KE / (s1x*s1x), KE / (s0y*s0y), KE / (s1y*s1y));
    P.q3 = make_float4(KE / (s0z*s0z), KE / (s1z*s1z), ph[p0] * INV2PI, ph[p1] * INV2PI);
    pp[j] = P;
}

// Each block: 256 points x (NPRIMS/NSPLIT) prims (as packed pairs).
// Prim data via wave-uniform s_load; per-pair math in packed fp32;
// sqrt/exp2/fract/sin/cos per-half on the trans pipe (R6-verified path).
// Only change vs R6: the max(d2,1e-12) clamp is dropped — d2 is a sum of
// squares (>= 0), v_sqrt is defined on [0,inf), and the clamp only matters
// when d2 < 1e-12 where the phase difference is ~1e-5 rad << bf16 floor.
template <int NSPLIT>
__global__ __launch_bounds__(BLK) void field_kernel(
        const float* __restrict__ qp,
        const PrimPair* __restrict__ pp,
        const void* __restrict__ freq_p,
        float2* __restrict__ part) {
    const int n = blockIdx.x * BLK + threadIdx.x;
    const float x = qp[3*n+0], y = qp[3*n+1], z = qp[3*n+2];
    const float kr = read_freq(freq_p) / 299792458.0f;   // cycles per metre
    const v2f kr2 = {kr, kr};

    constexpr int PAIRS = (NPRIMS / NSPLIT) / 2;   // 64 at NSPLIT=16
    const int base = blockIdx.y * PAIRS;

    v2f re = {0.0f, 0.0f}, im = {0.0f, 0.0f};
    const v2f xx = {x, x}, yy = {y, y}, zz = {z, z};

    #pragma unroll 4
    for (int j = 0; j < PAIRS; ++j) {
        PrimPair P = pp[base + j];                 // wave-uniform -> s_load
        v2f mux = {P.q0.x, P.q0.y}, muy = {P.q0.z, P.q0.w};
        v2f muz = {P.q1.x, P.q1.y}, am2 = {P.q1.z, P.q1.w};
        v2f gx  = {P.q2.x, P.q2.y}, gy  = {P.q2.z, P.q2.w};
        v2f gz  = {P.q3.x, P.q3.y}, ph2 = {P.q3.z, P.q3.w};

        v2f dx = xx - mux, dy = yy - muy, dz = zz - muz;
        v2f t0 = dx * dx, t1 = dy * dy, t2 = dz * dz;
        v2f e  = t0 * gx + t1 * gy + t2 * gz;      // <= 0; pk_fma chain
        v2f d2 = t0 + t1 + t2;                     // >= 0 by construction

        float r0 = __builtin_amdgcn_sqrtf(d2.x);
        float r1 = __builtin_amdgcn_sqrtf(d2.y);
        float e0 = __builtin_amdgcn_exp2f(e.x);
        float e1 = __builtin_amdgcn_exp2f(e.y);
        v2f r2 = {r0, r1};
        v2f ex = {e0, e1};
        v2f w2 = am2 * ex;
        v2f tp = __builtin_elementwise_fma(kr2, r2, ph2);   // revolutions
        float f0 = __builtin_amdgcn_fractf(tp.x);
        float f1 = __builtin_amdgcn_fractf(tp.y);
        float s0 = __builtin_amdgcn_sinf(f0);
        float s1 = __builtin_amdgcn_sinf(f1);
        float c0 = __builtin_amdgcn_cosf(f0);
        float c1 = __builtin_amdgcn_cosf(f1);
        v2f s2 = {s0, s1}, c2 = {c0, c1};
        re += w2 * c2;                             // pk_fma
        im += w2 * s2;                             // pk_fma
    }

    part[(size_t)blockIdx.y * NPOINTS + n] = make_float2(re.x + re.y, im.x + im.y);
}

template <int NSPLIT>
__global__ __launch_bounds__(BLK) void reduce_kernel(const float2* __restrict__ part,
                                                     float* __restrict__ out) {
    int n = blockIdx.x * blockDim.x + threadIdx.x;
    float re = 0.0f, im = 0.0f;
    #pragma unroll
    for (int s = 0; s < NSPLIT; ++s) {
        float2 v = part[(size_t)s * NPOINTS + n];
        re += v.x; im += v.y;
    }
    out[n]           = re;   // planar: real block then imag block
    out[NPOINTS + n] = im;
}

// Fallback (tiny workspace): LDS kernel, single pass, direct planar output.
__global__ __launch_bounds__(BLK) void field_fallback(
        const float* __restrict__ qp,
        const float* __restrict__ pos,
        const float* __restrict__ scl,
        const float* __restrict__ amp,
        const float* __restrict__ ph,
        const void*  __restrict__ freq_p,
        float*       __restrict__ out) {
    __shared__ float4 sA[128];
    __shared__ float4 sB[128];
    const int n = blockIdx.x * BLK + threadIdx.x;
    const float x = qp[3*n+0], y = qp[3*n+1], z = qp[3*n+2];
    const float kr = read_freq(freq_p) / 299792458.0f;
    const float KE = -0.72134752044448169f, INV2PI = 0.15915494309189535f;
    float re = 0.0f, im = 0.0f;
    for (int tile = 0; tile < NPRIMS / 128; ++tile) {
        __syncthreads();
        if (threadIdx.x < 128) {
            int p = tile * 128 + threadIdx.x;
            float sx = scl[3*p+0], sy = scl[3*p+1], sz = scl[3*p+2];
            sA[threadIdx.x] = make_float4(pos[3*p+0], pos[3*p+1], pos[3*p+2], amp[p]);
            sB[threadIdx.x] = make_float4(KE/(sx*sx), KE/(sy*sy), KE/(sz*sz), ph[p]*INV2PI);
        }
        __syncthreads();
        #pragma unroll 8
        for (int p = 0; p < 128; ++p) {
            float4 a = sA[p];
            float4 b = sB[p];
            float dx = x - a.x, dy = y - a.y, dz = z - a.z;
            float t0 = dx*dx, t1 = dy*dy, t2 = dz*dz;
            float e  = fmaf(t0, b.x, fmaf(t1, b.y, t2 * b.z));
            float d2 = t0 + t1 + t2;
            float r  = __builtin_amdgcn_sqrtf(d2);
            float w  = a.w * __builtin_amdgcn_exp2f(e);
            float tp = __builtin_amdgcn_fractf(fmaf(kr, r, b.w));
            float s  = __builtin_amdgcn_sinf(tp);
            float c  = __builtin_amdgcn_cosf(tp);
            re = fmaf(w, c, re);
            im = fmaf(w, s, im);
        }
    }
    out[n]           = re;
    out[NPOINTS + n] = im;
}

extern "C" void kernel_launch(void* const* d_in, const int* in_sizes, int n_in,
                              void* d_out, int out_size, void* d_ws, size_t ws_size,
                              hipStream_t stream) {
    const float* qp  = (const float*)d_in[0];
    const float* pos = (const float*)d_in[1];
    const float* scl = (const float*)d_in[2];
    const float* amp = (const float*)d_in[3];
    const float* ph  = (const float*)d_in[4];
    const void*  fq  = d_in[5];
    float* out = (float*)d_out;

    const size_t packed_bytes = (size_t)(NPRIMS / 2) * sizeof(PrimPair);      // 64 KB
    const size_t ps16 = packed_bytes + (size_t)16 * NPOINTS * sizeof(float2); // +4 MB

    if (ws_size >= ps16) {
        // exact round-6 configuration (best measured: 42.8 us field / 47.3 total)
        PrimPair* pp   = (PrimPair*)d_ws;
        float2*   part = (float2*)((char*)d_ws + packed_bytes);
        prep_kernel<<<dim3((NPRIMS/2 + BLK - 1) / BLK), dim3(BLK), 0, stream>>>(pos, scl, amp, ph, pp);
        field_kernel<16><<<dim3(PBLK, 16), dim3(BLK), 0, stream>>>(qp, pp, fq, part);
        reduce_kernel<16><<<dim3(NPOINTS / BLK), dim3(BLK), 0, stream>>>(part, out);
    } else {
        field_fallback<<<dim3(NPOINTS / BLK), dim3(BLK), 0, stream>>>(qp, pos, scl, amp, ph, fq, out);
    }
}